// Round 8
// baseline (2474.733 us; speedup 1.0000x reference)
//
#include <hip/hip_runtime.h>
#include <hip/hip_bf16.h>
#include <stdint.h>

#define T_N 8192
#define K_N 1024
#define D_N 1024
#define LMBDA 5.0f
#define BIGF 3.0e38f

// ---------------- norms: numpy-pairwise-exact sum of squares per row ----------------
__global__ __launch_bounds__(256) void k_norms(const float* __restrict__ F,
                                               const float* __restrict__ C,
                                               float* __restrict__ sf2,
                                               float* __restrict__ sc2) {
#pragma clang fp contract(off)
  int wave = threadIdx.x >> 6;
  int lane = threadIdx.x & 63;
  int row = blockIdx.x * 4 + wave;
  const float* src;
  float* dst;
  if (row < T_N) { src = F + (size_t)row * D_N; dst = sf2 + row; }
  else           { src = C + (size_t)(row - T_N) * D_N; dst = sc2 + (row - T_N); }
  int leaf = lane >> 3, j = lane & 7;
  const float* p = src + leaf * 128 + j;
  float x = p[0];
  float r = x * x;
#pragma unroll
  for (int i = 1; i < 16; ++i) {
    float y = p[8 * i];
    r = r + y * y;
  }
  r = r + __shfl_xor(r, 1, 64);
  r = r + __shfl_xor(r, 2, 64);
  r = r + __shfl_xor(r, 4, 64);
  r = r + __shfl_xor(r, 8, 64);
  r = r + __shfl_xor(r, 16, 64);
  r = r + __shfl_xor(r, 32, 64);
  if (lane == 0) *dst = r;
}

// ---------------- d2 GEMM: OpenBLAS-faithful f32 (numerics frozen — do not reorder) ----------------
__global__ __launch_bounds__(256) void k_gemm(const float* __restrict__ F,
                                              const float* __restrict__ C,
                                              const float* __restrict__ sf2,
                                              const float* __restrict__ sc2,
                                              float* __restrict__ d2) {
  __shared__ float As[32][68];
  __shared__ float Bs[32][68];
  int t0 = (int)(blockIdx.x >> 4) * 64;
  int k0 = (int)(blockIdx.x & 15) * 64;
  int tid = threadIdx.x;
  int tx = tid & 15, ty = tid >> 4;
  float acc[4][4], p0[4][4], p1[4][4];
#pragma unroll
  for (int i = 0; i < 4; ++i)
#pragma unroll
    for (int j = 0; j < 4; ++j) { acc[i][j] = 0.0f; p0[i][j] = 0.0f; p1[i][j] = 0.0f; }
  int r = tid & 63;
  int cbase = (tid >> 6) * 2;
  for (int d0 = 0; d0 < D_N; d0 += 32) {
    __syncthreads();
#pragma unroll
    for (int p = 0; p < 2; ++p) {
      int c4 = cbase + p;
      float4 va = *(const float4*)&F[(size_t)(t0 + r) * D_N + d0 + c4 * 4];
      As[c4 * 4 + 0][r] = va.x; As[c4 * 4 + 1][r] = va.y;
      As[c4 * 4 + 2][r] = va.z; As[c4 * 4 + 3][r] = va.w;
      float4 vb = *(const float4*)&C[(size_t)(k0 + r) * D_N + d0 + c4 * 4];
      Bs[c4 * 4 + 0][r] = vb.x; Bs[c4 * 4 + 1][r] = vb.y;
      Bs[c4 * 4 + 2][r] = vb.z; Bs[c4 * 4 + 3][r] = vb.w;
    }
    __syncthreads();
#pragma unroll
    for (int d = 0; d < 32; ++d) {
      float4 a = *(const float4*)&As[d][ty * 4];
      float4 b = *(const float4*)&Bs[d][tx * 4];
      acc[0][0] = fmaf(a.x, b.x, acc[0][0]); acc[0][1] = fmaf(a.x, b.y, acc[0][1]);
      acc[0][2] = fmaf(a.x, b.z, acc[0][2]); acc[0][3] = fmaf(a.x, b.w, acc[0][3]);
      acc[1][0] = fmaf(a.y, b.x, acc[1][0]); acc[1][1] = fmaf(a.y, b.y, acc[1][1]);
      acc[1][2] = fmaf(a.y, b.z, acc[1][2]); acc[1][3] = fmaf(a.y, b.w, acc[1][3]);
      acc[2][0] = fmaf(a.z, b.x, acc[2][0]); acc[2][1] = fmaf(a.z, b.y, acc[2][1]);
      acc[2][2] = fmaf(a.z, b.z, acc[2][2]); acc[2][3] = fmaf(a.z, b.w, acc[2][3]);
      acc[3][0] = fmaf(a.w, b.x, acc[3][0]); acc[3][1] = fmaf(a.w, b.y, acc[3][1]);
      acc[3][2] = fmaf(a.w, b.z, acc[3][2]); acc[3][3] = fmaf(a.w, b.w, acc[3][3]);
    }
    if (d0 == 352) {
#pragma unroll
      for (int i = 0; i < 4; ++i)
#pragma unroll
        for (int j = 0; j < 4; ++j) { p0[i][j] = acc[i][j]; acc[i][j] = 0.0f; }
    }
    if (d0 == 736) {
#pragma unroll
      for (int i = 0; i < 4; ++i)
#pragma unroll
        for (int j = 0; j < 4; ++j) { p1[i][j] = acc[i][j]; acc[i][j] = 0.0f; }
    }
  }
  {
#pragma clang fp contract(off)
#pragma unroll
    for (int i = 0; i < 4; ++i) {
      int t = t0 + ty * 4 + i;
      float sa = sf2[t];
      float o[4];
#pragma unroll
      for (int j = 0; j < 4; ++j) {
        float dot = (p0[i][j] + p1[i][j]) + acc[i][j];
        float two = 2.0f * dot;
        o[j] = (sa - two) + sc2[k0 + tx * 4 + j];
      }
      float4 ov; ov.x = o[0]; ov.y = o[1]; ov.z = o[2]; ov.w = o[3];
      *(float4*)&d2[(size_t)t * K_N + k0 + tx * 4] = ov;
    }
  }
}

// ---------------- dmin: exact per-row min of d2 (min is order-independent) ----------------
__global__ __launch_bounds__(256) void k_dmin(const float* __restrict__ d2,
                                              float* __restrict__ dminArr) {
  int wave = threadIdx.x >> 6;
  int lane = threadIdx.x & 63;
  int row = blockIdx.x * 4 + wave;
  const float4* p = (const float4*)(d2 + (size_t)row * K_N + lane * 16);
  float4 a = p[0], b = p[1], c = p[2], d = p[3];
  float m = fminf(fminf(fminf(a.x, a.y), fminf(a.z, a.w)),
                  fminf(fminf(b.x, b.y), fminf(b.z, b.w)));
  float n = fminf(fminf(fminf(c.x, c.y), fminf(c.z, c.w)),
                  fminf(fminf(d.x, d.y), fminf(d.z, d.w)));
  m = fminf(m, n);
  m = fminf(m, __shfl_xor(m, 1, 64));
  m = fminf(m, __shfl_xor(m, 2, 64));
  m = fminf(m, __shfl_xor(m, 4, 64));
  m = fminf(m, __shfl_xor(m, 8, 64));
  m = fminf(m, __shfl_xor(m, 16, 64));
  m = fminf(m, __shfl_xor(m, 32, 64));
  if (lane == 0) dminArr[row] = m;
}

// ---------------- DPP min chain (result valid in lane 63) ----------------
__device__ __forceinline__ float dpp_min_chain(float x) {
  int t;
  t = __builtin_amdgcn_update_dpp(__float_as_int(x), __float_as_int(x), 0x111, 0xF, 0xF, false);
  x = fminf(x, __int_as_float(t));
  t = __builtin_amdgcn_update_dpp(__float_as_int(x), __float_as_int(x), 0x112, 0xF, 0xF, false);
  x = fminf(x, __int_as_float(t));
  t = __builtin_amdgcn_update_dpp(__float_as_int(x), __float_as_int(x), 0x114, 0xF, 0xF, false);
  x = fminf(x, __int_as_float(t));
  t = __builtin_amdgcn_update_dpp(__float_as_int(x), __float_as_int(x), 0x118, 0xF, 0xF, false);
  x = fminf(x, __int_as_float(t));
  t = __builtin_amdgcn_update_dpp(__float_as_int(x), __float_as_int(x), 0x142, 0xF, 0xF, false); // row_bcast:15
  x = fminf(x, __int_as_float(t));
  t = __builtin_amdgcn_update_dpp(__float_as_int(x), __float_as_int(x), 0x143, 0xF, 0xF, false); // row_bcast:31
  x = fminf(x, __int_as_float(t));
  return x;
}
__device__ __forceinline__ float rdlane(float x, int l) {
  return __int_as_float(__builtin_amdgcn_readlane(__float_as_int(x), l));
}

// ---------------- pass1: 4-wave, G=2 pair-amortized exchange ----------------
// Exact-min algebra (all identities exact on f32 lattice; RN monotone, min selects):
//   A0=RN(d_t0+RN(f_prev-L)); B0=RN(d_t0+a_prev); A1=RN(d_t1+RN(A0-L)); B1=RN(d_t1+RN(B0-L))
//   f_t0 = min(A0,B0);  a_t0 = min(QA0,QB0)
//   f_t1 = min(A1,B1,RN(d_t1+a_t0));  a_t1 = min(QA1,QB1,RN(dmin_t1+a_t0))
// One barrier + one LDS round-trip per TWO steps. alphaOut bit-identical to reference.
__global__ __launch_bounds__(256, 1) void k_pass1(const float* __restrict__ d2,
                                                  const float* __restrict__ dminArr,
                                                  float* __restrict__ alphaOut) {
  __shared__ float4 ldsP[2][4];   // [pair parity][wave] = {qa0, qb0, qa1, qb1}
  const int tid = threadIdx.x;
  const int lane = tid & 63;
  const int wid = tid >> 6;
  const float* base = d2 + (size_t)(wid * 256 + lane * 4);
  float4 rg[8];     // 8-row prefetch ring, 1 float4/lane/row
#pragma unroll
  for (int u = 0; u < 8; ++u) rg[u] = *(const float4*)(base + (size_t)u * K_N);
  float fp0 = BIGF, fp1 = BIGF, fp2 = BIGF, fp3 = BIGF;  // f_prev (4 k's/lane)
  float alpha = 0.0f;   // a_{-1}
  float areg = 0.0f;
  float dmv_next = dminArr[lane];
  for (int b64 = 0; b64 < T_N; b64 += 64) {
    float dmv = dmv_next;
    int nb = b64 + 64; if (nb >= T_N) nb = 0;
    dmv_next = dminArr[nb + lane];
    for (int b8 = 0; b8 < 64; b8 += 8) {
#pragma unroll
      for (int u = 0; u < 4; ++u) {           // 4 pairs per 8-row block
        const int par = u & 1;                // pair parity (compile-time)
        int t0 = b64 + b8 + 2 * u;
        int t1 = t0 + 1;
        float4 dc0 = rg[2 * u];
        float4 dc1 = rg[2 * u + 1];
        // prefetch rows t0+8, t1+8 into the consumed slots
        int pr0 = t0 + 8; if (pr0 > T_N - 1) pr0 = T_N - 1;
        int pr1 = t1 + 8; if (pr1 > T_N - 1) pr1 = T_N - 1;
        rg[2 * u] = *(const float4*)(base + (size_t)pr0 * K_N);
        rg[2 * u + 1] = *(const float4*)(base + (size_t)pr1 * K_N);
        // alpha-free pair chains (exact)
        float A0x = dc0.x + (fp0 - LMBDA), A0y = dc0.y + (fp1 - LMBDA);
        float A0z = dc0.z + (fp2 - LMBDA), A0w = dc0.w + (fp3 - LMBDA);
        float B0x = dc0.x + alpha, B0y = dc0.y + alpha;
        float B0z = dc0.z + alpha, B0w = dc0.w + alpha;
        float A1x = dc1.x + (A0x - LMBDA), A1y = dc1.y + (A0y - LMBDA);
        float A1z = dc1.z + (A0z - LMBDA), A1w = dc1.w + (A0w - LMBDA);
        float B1x = dc1.x + (B0x - LMBDA), B1y = dc1.y + (B0y - LMBDA);
        float B1z = dc1.z + (B0z - LMBDA), B1w = dc1.w + (B0w - LMBDA);
        // 4 per-wave reduces (interleaved DPP chains)
        float qa0 = fminf(fminf(A0x, A0y), fminf(A0z, A0w));
        float qb0 = fminf(fminf(B0x, B0y), fminf(B0z, B0w));
        float qa1 = fminf(fminf(A1x, A1y), fminf(A1z, A1w));
        float qb1 = fminf(fminf(B1x, B1y), fminf(B1z, B1w));
        qa0 = dpp_min_chain(qa0);
        qb0 = dpp_min_chain(qb0);
        qa1 = dpp_min_chain(qa1);
        qb1 = dpp_min_chain(qb1);
        if (lane == 63) {
          float4 v; v.x = qa0; v.y = qb0; v.z = qa1; v.w = qb1;
          ldsP[par][wid] = v;
        }
        asm volatile("s_waitcnt lgkmcnt(0)" ::: "memory");
        __builtin_amdgcn_s_barrier();
        asm volatile("" ::: "memory");
        // combine partials (all lanes, broadcast reads)
        float4 w0 = ldsP[par][0], w1 = ldsP[par][1], w2 = ldsP[par][2], w3 = ldsP[par][3];
        float QA0 = fminf(fminf(w0.x, w1.x), fminf(w2.x, w3.x));
        float QB0 = fminf(fminf(w0.y, w1.y), fminf(w2.y, w3.y));
        float QA1 = fminf(fminf(w0.z, w1.z), fminf(w2.z, w3.z));
        float QB1 = fminf(fminf(w0.w, w1.w), fminf(w2.w, w3.w));
        float a0 = fminf(QA0, QB0);
        float sdm = rdlane(dmv, b8 + 2 * u + 1);       // dmin_t1 (SGPR-indexed)
        float a1 = fminf(fminf(QA1, QB1), sdm + a0);
        // f_prev' = f_t1 = min(A1, B1, d_t1 + a_t0)
        fp0 = fminf(fminf(A1x, B1x), dc1.x + a0);
        fp1 = fminf(fminf(A1y, B1y), dc1.y + a0);
        fp2 = fminf(fminf(A1z, B1z), dc1.z + a0);
        fp3 = fminf(fminf(A1w, B1w), dc1.w + a0);
        alpha = a1;
        // record alphas (wave 0), burst store every 64 steps
        if (wid == 0) {
          areg = ((t0 & 63) == lane) ? a0 : areg;
          areg = ((t1 & 63) == lane) ? a1 : areg;
          if ((t1 & 63) == 63) alphaOut[(t1 & ~63) + lane] = areg;
        }
      }
    }
  }
}

// ---------------- pass2: chunked warm-start replay per k (validated r1 == full-history r2) ----------------
#define CH 512
#define WARM 64
__global__ __launch_bounds__(256) void k_pass2(const float* __restrict__ d2,
                                               const float* __restrict__ AOUT,
                                               unsigned* __restrict__ pack) {
  int kb = blockIdx.x & 3;
  int tc = blockIdx.x >> 2;
  int k = kb * 256 + threadIdx.x;
  int ts = tc * CH;
  int start = ts - WARM; if (start < 0) start = 0;
  int end = ts + CH;
  __shared__ float lal[CH + WARM + 1];
  for (int i = threadIdx.x; i < end - start + 1; i += 256) {
    int idx = start - 1 + i;
    lal[i] = (idx < 0) ? 0.0f : AOUT[idx];
  }
  __syncthreads();
  float f = BIGF;
  unsigned s = 0;
#pragma unroll 4
  for (int tau = start; tau < end; ++tau) {
    float a_in = lal[tau - start];               // alpha before step tau
    float d = d2[(size_t)tau * K_N + k];
    float ext = f - LMBDA;
    if (a_in < ext) s = (unsigned)tau;           // take_new -> segment restarts at tau
    f = d + fminf(a_in, ext);                    // identical rounding to reference
    if (tau >= ts) {
      float a_out = lal[tau - start + 1];        // alpha after step tau
      if (f == a_out) atomicMin(&pack[tau], ((unsigned)k << 13) | s);  // first-min-k wins
    }
  }
}

// ---------------- backtrack: ballot run-skip serial chase + parallel fill (validated r1) ----------------
__global__ __launch_bounds__(256) void k_backtrack(const unsigned* __restrict__ pack,
                                                   unsigned* __restrict__ unitsWs,
                                                   float* __restrict__ outUnits) {
  __shared__ unsigned lp[T_N];
  __shared__ unsigned long long msk[T_N / 64];
  int tid = threadIdx.x;
  for (int i = tid * 4; i < T_N; i += 1024) {
    *(uint4*)&lp[i] = *(const uint4*)&pack[i];
  }
  __syncthreads();
  if (tid < 64) {
    int lane = tid;
    int cur = T_N;
    for (int B = T_N - 64; B >= 0; B -= 64) {
      unsigned long long marks = 0ull;
      if (cur > B) {
        unsigned pk = lp[B + lane];
        int bv = (int)(pk & 8191u);
        unsigned long long run = __ballot(bv == B + lane);  // beta==idx: descend-by-1
        while (cur > B) {
          int L = cur - 1 - B;
          unsigned long long below = (L == 63) ? ~0ull : ((1ull << (L + 1)) - 1ull);
          unsigned long long nz = (~run) & below;
          if (nz == 0ull) { marks |= below; cur = B; break; }
          int j = 63 - __builtin_clzll(nz);                  // first non-run lane <= L
          marks |= below & ~((1ull << j) - 1ull);            // visit [j, L]
          int nb = __builtin_amdgcn_readlane(bv, j);         // jump
          cur = nb;
          if (cur > B + j) cur = B + j;                      // defensive: force progress
        }
      }
      if (lane == 0) msk[B >> 6] = marks;
    }
  }
  __syncthreads();
  // units[p] = gamma at the smallest chain mark >= p
  for (int p = tid; p < T_N; p += 256) {
    int w = p >> 6;
    unsigned long long m = msk[w] & (~0ull << (p & 63));
    while (m == 0ull) { ++w; m = msk[w]; }
    int idx = (w << 6) + (int)__builtin_ctzll(m);
    unsigned g = (lp[idx] >> 13) & 1023u;
    unitsWs[p] = g;
    outUnits[p] = (float)g;
  }
}

// ---------------- gather: quantized[t] = codebook[units[t]] ----------------
__global__ __launch_bounds__(256) void k_gather(const float* __restrict__ C,
                                                const unsigned* __restrict__ unitsWs,
                                                float* __restrict__ out) {
  int t = blockIdx.x;
  unsigned u = unitsWs[t] & 1023u;
  const float4* src = (const float4*)(C + (size_t)u * D_N);
  float4* dst = (float4*)(out + (size_t)t * D_N);
  dst[threadIdx.x] = src[threadIdx.x];
}

extern "C" void kernel_launch(void* const* d_in, const int* in_sizes, int n_in,
                              void* d_out, int out_size, void* d_ws, size_t ws_size,
                              hipStream_t stream) {
  const float* F = (const float*)d_in[0];
  const float* C = (const float*)d_in[1];
  float* out = (float*)d_out;
  float* d2 = out;                                  // reuse quantized region as d2 scratch
  float* outUnits = out + (size_t)T_N * D_N;
  char* ws = (char*)d_ws;
  float* alphaOut = (float*)(ws);                    // 32 KB
  unsigned* pack = (unsigned*)(ws + (32 << 10));     // 32 KB
  unsigned* unitsWs = (unsigned*)(ws + (64 << 10));  // 32 KB
  float* sf2 = (float*)(ws + (96 << 10));            // 32 KB
  float* sc2 = (float*)(ws + (128 << 10));           // 4 KB
  float* dminArr = (float*)(ws + (160 << 10));       // 32 KB

  k_norms<<<(T_N + K_N) / 4, 256, 0, stream>>>(F, C, sf2, sc2);
  hipMemsetAsync(pack, 0xFF, T_N * sizeof(unsigned), stream);
  k_gemm<<<(T_N / 64) * (K_N / 64), 256, 0, stream>>>(F, C, sf2, sc2, d2);
  k_dmin<<<T_N / 4, 256, 0, stream>>>(d2, dminArr);
  k_pass1<<<1, 256, 0, stream>>>(d2, dminArr, alphaOut);
  k_pass2<<<(T_N / CH) * 4, 256, 0, stream>>>(d2, alphaOut, pack);
  k_backtrack<<<1, 256, 0, stream>>>(pack, unitsWs, outUnits);
  k_gather<<<T_N, 256, 0, stream>>>(C, unitsWs, out);
}